// Round 13
// baseline (355.816 us; speedup 1.0000x reference)
//
#include <hip/hip_runtime.h>
#include <cstdint>

// Problem constants
#define Bn   32
#define Cn   256
#define Hn   56
#define Wn   56
#define HWn  (Hn*Wn)           // 3136
#define NPIX (Bn*HWn)          // 100352
#define WELEMS (Cn*Cn*9)       // 589824
#define EPSv 1e-5f

// padded channels-last activation plane: [b][58 rows][58 cols][256 ci] i8
// per-pixel 256B block stored XOR-swizzled: 16B slot s lives at s ^ (padded_col & 15)
#define PR   58
#define PPLANE (PR*PR)         // 3364

// ws layout (floats): [8..152) = 144 per-block |w| partials (plain stores);
// [160..416) = F_SUM; [416..672) = F_SQ (zeroed by pack tail blocks).
#define F_WPART 8
#define F_SUM   160
#define F_SQ    416
#define WPK_OFF  4096              // i8 wpk[kc=36(+4 pad)][co=256][64]
#define WPK_SLOTS 40
#define ACT_OFF  (WPK_OFF + WPK_SLOTS*16384)   // 659456 (16B aligned)
#define ACT_BYTES (Bn*PPLANE*Cn)   // 27553792

typedef int v4i __attribute__((ext_vector_type(4)));

#define GLOBAL_AS __attribute__((address_space(1)))
#define LDS_AS    __attribute__((address_space(3)))

// sign byte: 0x01 for non-negative, 0xFF for negative (matches prior rounds)
__device__ __forceinline__ uint32_t sgnbyte(float f) {
    return (__float_as_uint(f) >> 31) ? 0xFFu : 0x01u;
}

// ---------------------------------------------------------------------------
// Packing kernel, round-13: float4-read activation pack with in-register
// 4x4 byte transpose. 64-thread blocks.
//   [0,1568)     act pack: block = (batch b, 64 pixels). 4-lane group g owns
//                pixels p0+4g..p0+4g+3; per round, lane i loads float4
//                (4 px) of channel 4r+i; 2x shfl_xor + byte_perm transpose
//                -> lane i holds dword (4 ch) of pixel p0+4g+i. 4 rounds =
//                one 16B slot -> swizzled uint4 store (R8-verified write
//                pattern: one thread writes its whole 256B pixel block).
//                Read: 64 float4/thread (16B/lane) vs 256 scalar dwords.
//   [1568,1712)  weight repack -> 144 partials
//   [1712,1826)  halo zeroing (7296 border pixels)
//   [1826,1834)  BN-stats zero-init (512 floats)
__global__ void pack_all(const float* __restrict__ x,
                         const float* __restrict__ w,
                         float* __restrict__ wsf,
                         uint8_t* __restrict__ wpk,
                         uint8_t* __restrict__ act) {
    const int t = threadIdx.x;                 // 0..63
    if (blockIdx.x < 1568) {
        const int bx = blockIdx.x;
        const int b  = bx / 49;
        const int p0 = (bx - b * 49) * 64;
        const int lo = t & 3;                  // lane-in-group = channel offset / owned px offset
        const int g  = t >> 2;                 // group = pixel quad

        // this lane's LOAD base: channel stream (4r+lo), pixel quad p0+4g
        const float* xbase = x + (size_t)b * Cn * HWn + p0 + g * 4;
        // this lane's OWNED pixel (post-transpose)
        const int px = p0 + g * 4 + lo;
        const int y  = px / Wn;
        const int xx = px - y * Wn;
        const int key = (xx + 1) & 15;
        uint32_t* dst = (uint32_t*)(act + ((size_t)(b * PR + (y + 1)) * PR + (xx + 1)) * 256);

        const uint32_t sel1 = (t & 1) ? 0x3715u : 0x6240u;
        const uint32_t sel2 = (t & 2) ? 0x3276u : 0x5410u;

        #pragma unroll
        for (int sl = 0; sl < 16; sl++) {
            uint32_t q[4];
            #pragma unroll
            for (int rr = 0; rr < 4; rr++) {
                int c = sl * 16 + rr * 4 + lo;
                float4 v = *(const float4*)(xbase + (size_t)c * HWn);
                // px-major sign bytes: byte j = pixel p0+4g+j of channel c
                uint32_t d = sgnbyte(v.x) | (sgnbyte(v.y) << 8) |
                             (sgnbyte(v.z) << 16) | (sgnbyte(v.w) << 24);
                // 4x4 byte transpose across the 4-lane group
                uint32_t p1 = (uint32_t)__shfl_xor((int)d, 1);
                uint32_t e  = __byte_perm(d, p1, sel1);
                uint32_t p2 = (uint32_t)__shfl_xor((int)e, 2);
                q[rr] = __byte_perm(e, p2, sel2);   // ch 4r..4r+3 (byte0=lowest) of px
            }
            *(uint4*)(dst + (size_t)((sl ^ key) * 4)) = make_uint4(q[0], q[1], q[2], q[3]);
        }
    } else if (blockIdx.x < 1712) {
        int u = (blockIdx.x - 1568) * 64 + t;   // 144*64 = 9216
        int co = u / 36;
        int kc = u - co * 36;
        int tp = kc >> 2;          // tap
        int s  = kc & 3;           // 64-ci chunk
        const float* wp = w + (size_t)co * 2304 + tp;     // OIHW
        uint32_t* dst = (uint32_t*)(wpk + ((size_t)kc * 256 + co) * 64);
        float sabs = 0.0f;
        #pragma unroll
        for (int cw = 0; cw < 16; cw++) {
            uint32_t r = 0;
            #pragma unroll
            for (int j = 0; j < 4; j++) {
                int ci = s * 64 + cw * 4 + j;
                float wv = wp[(size_t)ci * 9];
                sabs += fminf(fabsf(wv), 1.0f);
                r |= ((__float_as_uint(wv) >> 31) ? 0xFFu : 0x01u) << (j * 8);
            }
            dst[cw] = r;
        }
        #pragma unroll
        for (int off = 32; off; off >>= 1) sabs += __shfl_down(sabs, off);
        if (t == 0)   // plain store: no atomic, no init required
            wsf[F_WPART + (blockIdx.x - 1568)] = sabs;
    } else if (blockIdx.x < 1826) {
        // --- halo zeroing: 32 batches * 228 border pixels = 7296 ---
        int hv = (blockIdx.x - 1712) * 64 + t;
        int b = hv / 228;
        int r = hv - b * 228;
        int y, xx;
        if (r < 58)       { y = 0;  xx = r; }
        else if (r < 116) { y = 57; xx = r - 58; }
        else { int r2 = r - 116; y = 1 + (r2 >> 1); xx = (r2 & 1) * 57; }
        uint4* d = (uint4*)(act + ((size_t)(b * PR + y) * PR + xx) * 256);
        uint4 z = make_uint4(0, 0, 0, 0);
        #pragma unroll
        for (int i = 0; i < 16; i++) d[i] = z;
    } else {
        // --- BN-stats zero-init: 512 floats at F_SUM ---
        int idx = (blockIdx.x - 1826) * 64 + t;
        wsf[F_SUM + idx] = 0.0f;
    }
}

// ---------------------------------------------------------------------------
// Binary conv as implicit GEMM on the i8 matrix pipe, LDS-staged B.
// FROZEN (R8/R11/R12 local optimum ~126us): 4 waves, wave tile 64co x 112px,
// depth-4 A-pipeline, single bf, runtime t-loop, global_load_lds staging,
// T1 XCD swizzle (FETCH -21%), T5 setprio, padded-wpk affine prefetch.
__global__ __launch_bounds__(256, 2) void conv_mfma(
    const uint8_t* __restrict__ act, const uint8_t* __restrict__ wpk,
    const float* __restrict__ x, float* __restrict__ wsf,
    float* __restrict__ out) {
    __shared__ uint4 ldsv[3712];              // 59392 B = 58 chunks of 1KB
    uint8_t* lds = (uint8_t*)ldsv;

    const int tid  = threadIdx.x;
    const int lane = tid & 63;
    const int wid  = tid >> 6;                // 0..3
    const int l15  = lane & 15;
    const int l4   = lane >> 4;               // 0..3

    // XCD-aware swizzle: XCD k gets the contiguous tile range [k*112,(k+1)*112).
    const int bxr = blockIdx.x;               // 0..895
    const int bx  = (bxr & 7) * 112 + (bxr >> 3);
    const int b   = bx / 28;
    const int y0  = (bx - b * 28) * 2;        // first output image row

    // Stage padded rows y0..y0+3 via async global->LDS DMA: 58 x 1KB chunks.
    {
        const uint8_t* src = act + ((size_t)b * PR + y0) * PR * 256;
        #pragma unroll
        for (int j = 0; j < 15; j++) {
            int c = wid + j * 4;               // wave-uniform
            if (c < 58) {
                __builtin_amdgcn_global_load_lds(
                    (const GLOBAL_AS uint32_t*)(const void*)(src + c * 1024 + lane * 16),
                    (LDS_AS uint32_t*)(void*)(lds + c * 1024),
                    16, 0, 0);
            }
        }
    }

    // A-fragment lane base (co = wid*64 + mi*16 + l15, bytes l4*16)
    const uint8_t* abase = wpk + (wid * 64 + l15) * 64 + l4 * 16;

    // Pipeline prologue: fill the 4 A-buffers with kc = 0..3.
    v4i af0[4], af1[4], af2[4], af3[4];
    #pragma unroll
    for (int mi = 0; mi < 4; mi++) {
        af0[mi] = *(const v4i*)(abase + (size_t)0 * 16384 + mi * 1024);
        af1[mi] = *(const v4i*)(abase + (size_t)1 * 16384 + mi * 1024);
        af2[mi] = *(const v4i*)(abase + (size_t)2 * 16384 + mi * 1024);
        af3[mi] = *(const v4i*)(abase + (size_t)3 * 16384 + mi * 1024);
    }

    // Tap-walking state for t=0 (dh=-1, dw=-1): window corner (r_, c_) local.
    int pixb[7], key[7];
    #pragma unroll
    for (int ni = 0; ni < 7; ni++) {
        int n  = ni * 16 + l15;
        int r_ = n / 56;
        int c_ = n - r_ * 56;
        pixb[ni] = (r_ * 58 + c_) * 256;
        key[ni]  = c_ & 15;
    }

    __syncthreads();   // drains vmcnt(0): LDS-DMA chunks + af loads all ready

    v4i acc[4][7] = {};

// STEP: load bf for sub-step S, run 28 MFMAs (priority-boosted) on the
// resident AF buffer, then reload AF with K-chunk t4+S+4 (affine, pad-safe).
#define STEP(S, AF)                                                            \
    {                                                                          \
        v4i bf[7];                                                             \
        _Pragma("unroll")                                                      \
        for (int ni = 0; ni < 7; ni++)                                         \
            bf[ni] = *(const v4i*)(lds + pixb[ni] +                            \
                                   ((((S) * 4 + l4) ^ key[ni]) << 4));         \
        __builtin_amdgcn_s_setprio(1);                                         \
        _Pragma("unroll")                                                      \
        for (int ni = 0; ni < 7; ni++) {                                       \
            _Pragma("unroll")                                                  \
            for (int mi = 0; mi < 4; mi++)                                     \
                acc[mi][ni] = __builtin_amdgcn_mfma_i32_16x16x64_i8(           \
                    AF[mi], bf[ni], acc[mi][ni], 0, 0, 0);                     \
        }                                                                      \
        __builtin_amdgcn_s_setprio(0);                                         \
        {                                                                      \
            const uint8_t* ap = abase + (size_t)(t4 + (S) + 4) * 16384;        \
            _Pragma("unroll")                                                  \
            for (int mi = 0; mi < 4; mi++)                                     \
                AF[mi] = *(const v4i*)(ap + mi * 1024);                        \
        }                                                                      \
    }

    #pragma unroll 1
    for (int t = 0; t < 9; t++) {
        const int t4 = t * 4;
        STEP(0, af0)
        STEP(1, af1)
        STEP(2, af2)
        STEP(3, af3)
        // Tap-walk t -> t+1: dw cycles -1,0,1 (ddw=+1, dtoff=+256), wrapping
        // at t=2,5 (ddw=-2, dtoff=(58-2)*256); t=8 is the end (no-op).
        const int wrap  = (t == 2 || t == 5);
        const int dtoff = (t == 8) ? 0 : (wrap ? 56 * 256 : 256);
        const int ddw   = (t == 8) ? 0 : (wrap ? -2 : 1);
        #pragma unroll
        for (int ni = 0; ni < 7; ni++) {
            pixb[ni] += dtoff;
            key[ni]   = (key[ni] + ddw) & 15;
        }
    }
#undef STEP

    // mean(|clip(w)|) from the 144 per-block partials (uniform, cheap).
    float wabs = 0.0f;
    #pragma unroll
    for (int j = 0; j < 144; j++) wabs += wsf[F_WPART + j];
    const float mv = wabs * (1.0f / (float)WELEMS);

    const int co_w = wid * 64;
    const int pbase = b * (Cn * HWn) + y0 * 56;

    // Epilogue: scale + shortcut + store + per-channel partial stats.
    float ssum[4][4] = {}, ssq[4][4] = {};
    #pragma unroll
    for (int mi = 0; mi < 4; mi++) {
        #pragma unroll
        for (int ni = 0; ni < 7; ni++) {
            v4i a = acc[mi][ni];
            #pragma unroll
            for (int q = 0; q < 4; q++) {
                int co = co_w + mi * 16 + l4 * 4 + q;
                size_t idx = (size_t)pbase + (size_t)co * HWn + (ni * 16 + l15);
                float val = fmaf(mv, (float)a[q], x[idx]);
                out[idx] = val;
                ssum[mi][q] += val;
                ssq[mi][q]  += val * val;
            }
        }
    }
    // Reduce across the 16 lanes (l15) sharing each channel, then atomics.
    #pragma unroll
    for (int mi = 0; mi < 4; mi++) {
        #pragma unroll
        for (int q = 0; q < 4; q++) {
            float s = ssum[mi][q], sq = ssq[mi][q];
            #pragma unroll
            for (int off = 1; off < 16; off <<= 1) {
                s  += __shfl_xor(s, off);
                sq += __shfl_xor(sq, off);
            }
            if (l15 == 0) {
                int co = co_w + mi * 16 + l4 * 4 + q;
                atomicAdd(&wsf[F_SUM + co], s);
                atomicAdd(&wsf[F_SQ  + co], sq);
            }
        }
    }
}

// ---------------------------------------------------------------------------
// BN finalize (per-plane, from fused stats) + normalize + ReLU, in place.
__global__ void epilogue_kernel(float* __restrict__ out,
                                const float* __restrict__ wsf,
                                const float* __restrict__ g,
                                const float* __restrict__ bt) {
    int plane = blockIdx.x;   // b*256 + c
    int c = plane & 255;
    const float n = (float)(Bn * HWn);
    float mean = wsf[F_SUM + c] / n;
    float var  = wsf[F_SQ + c] / n - mean * mean;
    float sc = g[c] * rsqrtf(var + EPSv);
    float sh = bt[c] - mean * sc;
    float4* o4 = (float4*)(out + (size_t)plane * HWn);
    for (int i = threadIdx.x; i < HWn / 4; i += 256) {
        float4 v = o4[i];
        v.x = fmaxf(fmaf(v.x, sc, sh), 0.0f);
        v.y = fmaxf(fmaf(v.y, sc, sh), 0.0f);
        v.z = fmaxf(fmaf(v.z, sc, sh), 0.0f);
        v.w = fmaxf(fmaf(v.w, sc, sh), 0.0f);
        o4[i] = v;
    }
}

// ---------------------------------------------------------------------------
extern "C" void kernel_launch(void* const* d_in, const int* in_sizes, int n_in,
                              void* d_out, int out_size, void* d_ws, size_t ws_size,
                              hipStream_t stream) {
    const float* x     = (const float*)d_in[0];
    const float* w     = (const float*)d_in[1];
    const float* gamma = (const float*)d_in[2];
    const float* beta  = (const float*)d_in[3];
    float* out = (float*)d_out;

    float*   wsf = (float*)d_ws;
    uint8_t* wpk = (uint8_t*)d_ws + WPK_OFF;
    uint8_t* act = (uint8_t*)d_ws + ACT_OFF;

    pack_all<<<dim3(1834), dim3(64), 0, stream>>>(x, w, wsf, wpk, act);
    conv_mfma<<<dim3(896), dim3(256), 0, stream>>>(act, wpk, x, wsf, out);
    epilogue_kernel<<<dim3(Bn * Cn), dim3(256), 0, stream>>>(out, wsf, gamma, beta);
}